// Round 1
// baseline (245.941 us; speedup 1.0000x reference)
//
#include <hip/hip_runtime.h>
#include <hip/hip_bf16.h>
#include <stdint.h>

#define B_N 4
#define NQ 1024
#define NKV 2048
#define DI 1024
#define H 16
#define DH 64

using bf16 = __bf16;
typedef bf16 bf16x8 __attribute__((ext_vector_type(8)));
typedef bf16 bf16x4 __attribute__((ext_vector_type(4)));
typedef float f32x4 __attribute__((ext_vector_type(4)));

typedef const __attribute__((address_space(1))) void* gptr_t;
typedef __attribute__((address_space(3))) void* sptr_t;

// ---------------- f32 -> bf16 convert ----------------
__global__ __launch_bounds__(256) void cvt_kernel(const float* __restrict__ in,
                                                  bf16* __restrict__ out, int n4) {
  int i = blockIdx.x * blockDim.x + threadIdx.x;
  if (i < n4) {
    float4 v = reinterpret_cast<const float4*>(in)[i];
    bf16x4 o;
    o[0] = (bf16)v.x; o[1] = (bf16)v.y; o[2] = (bf16)v.z; o[3] = (bf16)v.w;
    reinterpret_cast<bf16x4*>(out)[i] = o;
  }
}

// ---------------- LayerNorm (rows of 1024 f32) -> bf16 ----------------
__global__ __launch_bounds__(256) void ln_kernel(const float* __restrict__ x,
    const float* __restrict__ gamma, const float* __restrict__ beta,
    bf16* __restrict__ out) {
  int row = blockIdx.x;
  int t = threadIdx.x;
  const float4 v = reinterpret_cast<const float4*>(x + (size_t)row * 1024)[t];
  float s = v.x + v.y + v.z + v.w;
  float s2 = v.x*v.x + v.y*v.y + v.z*v.z + v.w*v.w;
#pragma unroll
  for (int m = 1; m < 64; m <<= 1) { s += __shfl_xor(s, m); s2 += __shfl_xor(s2, m); }
  __shared__ float red[8];
  int wid = t >> 6;
  if ((t & 63) == 0) { red[wid] = s; red[wid + 4] = s2; }
  __syncthreads();
  float ts  = red[0] + red[1] + red[2] + red[3];
  float ts2 = red[4] + red[5] + red[6] + red[7];
  float mean = ts * (1.0f / 1024.0f);
  float var  = ts2 * (1.0f / 1024.0f) - mean * mean;
  float rstd = rsqrtf(var + 1e-5f);
  float4 g  = reinterpret_cast<const float4*>(gamma)[t];
  float4 bb = reinterpret_cast<const float4*>(beta)[t];
  bf16x4 o;
  o[0] = (bf16)((v.x - mean) * rstd * g.x + bb.x);
  o[1] = (bf16)((v.y - mean) * rstd * g.y + bb.y);
  o[2] = (bf16)((v.z - mean) * rstd * g.z + bb.z);
  o[3] = (bf16)((v.w - mean) * rstd * g.w + bb.w);
  reinterpret_cast<bf16x4*>(out + (size_t)row * 1024)[t] = o;
}

// ---------------- GEMM: C[m,n] = sum_k A[m,k]*Bm[n,k]  (A: MxK, Bm: NxK, K=1024) ----
// MODE 0: bf16 out, *0.125 (qp)
// MODE 1: kv split -> out0 = K (B,NKV,DI) bf16, out1 = V^T (B,DI,NKV) bf16
// MODE 2: f32 out + bias (proj)
template<int MODE>
__global__ __launch_bounds__(256) void gemm_bt(const bf16* __restrict__ A,
    const bf16* __restrict__ Bm, void* __restrict__ out0, void* __restrict__ out1,
    const float* __restrict__ bias, int M, int N) {
  constexpr int K = 1024;
  __shared__ bf16 lA[128 * 32];
  __shared__ bf16 lB[128 * 32];
  const int nbn = N >> 7;
  const int bm = blockIdx.x / nbn, bn = blockIdx.x - bm * nbn;
  const int m0 = bm << 7, n0 = bn << 7;
  const int tid = threadIdx.x;
  const int lane = tid & 63, wid = tid >> 6;
  const int wr = wid >> 1, wc = wid & 1;
  const int l15 = lane & 15, lg = lane >> 4;

  f32x4 acc[4][4] = {};

  const int c0 = tid, c1 = tid + 256;
  const bf16* gA0 = A  + (size_t)(m0 + (c0 >> 2)) * K + ((c0 & 3) << 3);
  const bf16* gA1 = A  + (size_t)(m0 + (c1 >> 2)) * K + ((c1 & 3) << 3);
  const bf16* gB0 = Bm + (size_t)(n0 + (c0 >> 2)) * K + ((c0 & 3) << 3);
  const bf16* gB1 = Bm + (size_t)(n0 + (c1 >> 2)) * K + ((c1 & 3) << 3);

  for (int k0 = 0; k0 < K; k0 += 32) {
    __builtin_amdgcn_global_load_lds((gptr_t)(gA0 + k0), (sptr_t)(lA + c0 * 8), 16, 0, 0);
    __builtin_amdgcn_global_load_lds((gptr_t)(gA1 + k0), (sptr_t)(lA + c1 * 8), 16, 0, 0);
    __builtin_amdgcn_global_load_lds((gptr_t)(gB0 + k0), (sptr_t)(lB + c0 * 8), 16, 0, 0);
    __builtin_amdgcn_global_load_lds((gptr_t)(gB1 + k0), (sptr_t)(lB + c1 * 8), 16, 0, 0);
    __syncthreads();
    bf16x8 af[4], bfr[4];
#pragma unroll
    for (int i = 0; i < 4; ++i) {
      af[i]  = *reinterpret_cast<const bf16x8*>(lA + (wr * 64 + i * 16 + l15) * 32 + lg * 8);
      bfr[i] = *reinterpret_cast<const bf16x8*>(lB + (wc * 64 + i * 16 + l15) * 32 + lg * 8);
    }
#pragma unroll
    for (int i = 0; i < 4; ++i)
#pragma unroll
      for (int j = 0; j < 4; ++j)
        acc[i][j] = __builtin_amdgcn_mfma_f32_16x16x32_bf16(af[i], bfr[j], acc[i][j], 0, 0, 0);
    __syncthreads();
  }

  const int mB = m0 + wr * 64 + lg * 4;   // + i*16 + r
  const int nB = n0 + wc * 64 + l15;      // + j*16
  if constexpr (MODE == 0) {
    bf16* o = reinterpret_cast<bf16*>(out0);
#pragma unroll
    for (int i = 0; i < 4; ++i)
#pragma unroll
      for (int j = 0; j < 4; ++j)
#pragma unroll
        for (int r = 0; r < 4; ++r)
          o[(size_t)(mB + i * 16 + r) * N + nB + j * 16] = (bf16)(acc[i][j][r] * 0.125f);
  } else if constexpr (MODE == 2) {
    float* o = reinterpret_cast<float*>(out0);
#pragma unroll
    for (int j = 0; j < 4; ++j) {
      float bj = bias[nB + j * 16];
#pragma unroll
      for (int i = 0; i < 4; ++i)
#pragma unroll
        for (int r = 0; r < 4; ++r)
          o[(size_t)(mB + i * 16 + r) * N + nB + j * 16] = acc[i][j][r] + bj;
    }
  } else {
    if (n0 < 1024) {  // K part: (B,NKV,DI) flat = m*1024 + n
      bf16* o = reinterpret_cast<bf16*>(out0);
#pragma unroll
      for (int i = 0; i < 4; ++i)
#pragma unroll
        for (int j = 0; j < 4; ++j)
#pragma unroll
          for (int r = 0; r < 4; ++r)
            o[(size_t)(mB + i * 16 + r) * 1024 + nB + j * 16] = (bf16)acc[i][j][r];
    } else {          // V part transposed: (B,DI,NKV)
      bf16* o = reinterpret_cast<bf16*>(out1);
#pragma unroll
      for (int i = 0; i < 4; ++i) {
        int m = mB + i * 16;            // global row = b*2048 + kv  (kv mult of 4)
        int bb_ = m >> 11, kv = m & 2047;
#pragma unroll
        for (int j = 0; j < 4; ++j) {
          int nv = nB + j * 16 - 1024;  // d index within DI
          bf16x4 pk;
          pk[0] = (bf16)acc[i][j][0]; pk[1] = (bf16)acc[i][j][1];
          pk[2] = (bf16)acc[i][j][2]; pk[3] = (bf16)acc[i][j][3];
          *reinterpret_cast<bf16x4*>(o + ((size_t)(bb_ << 10) + nv) * 2048 + kv) = pk;
        }
      }
    }
  }
}

// ---------------- Flash attention ----------------
__device__ __forceinline__ float red16_max(float v) {
  v = fmaxf(v, __shfl_xor(v, 1));
  v = fmaxf(v, __shfl_xor(v, 2));
  v = fmaxf(v, __shfl_xor(v, 4));
  v = fmaxf(v, __shfl_xor(v, 8));
  return v;
}
__device__ __forceinline__ float red16_sum(float v) {
  v += __shfl_xor(v, 1); v += __shfl_xor(v, 2);
  v += __shfl_xor(v, 4); v += __shfl_xor(v, 8);
  return v;
}

// qp: (B,NQ,DI) bf16 (pre-scaled by 0.125), kk: (B,NKV,DI) bf16, vT: (B,DI,NKV) bf16
// out: (B,NQ,DI) bf16
__global__ __launch_bounds__(256) void attn_kernel(const bf16* __restrict__ qp,
    const bf16* __restrict__ kk, const bf16* __restrict__ vT, bf16* __restrict__ out) {
  __shared__ bf16 lP[4][32 * 64];
  const int bh = blockIdx.x;
  const int b = bh >> 4, h = bh & 15;
  const int qt = blockIdx.y;
  const int tid = threadIdx.x;
  const int lane = tid & 63, w = tid >> 6;
  const int l15 = lane & 15, lg = lane >> 4;
  const int q0 = qt * 128 + w * 32;

  const bf16* Qb = qp + (size_t)(b * NQ + q0) * DI + h * DH;
  const bf16* Kb = kk + (size_t)b * NKV * DI + h * DH;
  const bf16* Vb = vT + (size_t)(b * DI + h * DH) * NKV;

  bf16x8 qf[2][2];
#pragma unroll
  for (int mi = 0; mi < 2; ++mi)
#pragma unroll
    for (int ks = 0; ks < 2; ++ks)
      qf[mi][ks] = *reinterpret_cast<const bf16x8*>(Qb + (size_t)(mi * 16 + l15) * DI + ks * 32 + lg * 8);

  f32x4 o[2][4] = {};
  float mrun[2][4], lrun[2][4];
#pragma unroll
  for (int mi = 0; mi < 2; ++mi)
#pragma unroll
    for (int r = 0; r < 4; ++r) { mrun[mi][r] = -1e30f; lrun[mi][r] = 0.0f; }

  for (int kv0 = 0; kv0 < NKV; kv0 += 64) {
    bf16x8 kf[4][2];
#pragma unroll
    for (int ni = 0; ni < 4; ++ni)
#pragma unroll
      for (int ks = 0; ks < 2; ++ks)
        kf[ni][ks] = *reinterpret_cast<const bf16x8*>(Kb + (size_t)(kv0 + ni * 16 + l15) * DI + ks * 32 + lg * 8);

    f32x4 s[2][4] = {};
#pragma unroll
    for (int mi = 0; mi < 2; ++mi)
#pragma unroll
      for (int ni = 0; ni < 4; ++ni)
#pragma unroll
        for (int ks = 0; ks < 2; ++ks)
          s[mi][ni] = __builtin_amdgcn_mfma_f32_16x16x32_bf16(qf[mi][ks], kf[ni][ks], s[mi][ni], 0, 0, 0);

    float corr[2][4];
#pragma unroll
    for (int mi = 0; mi < 2; ++mi)
#pragma unroll
      for (int r = 0; r < 4; ++r) {
        float rm = fmaxf(fmaxf(s[mi][0][r], s[mi][1][r]), fmaxf(s[mi][2][r], s[mi][3][r]));
        rm = red16_max(rm);
        float mnew = fmaxf(mrun[mi][r], rm);
        corr[mi][r] = __expf(mrun[mi][r] - mnew);
        mrun[mi][r] = mnew;
      }
#pragma unroll
    for (int mi = 0; mi < 2; ++mi)
#pragma unroll
      for (int ni = 0; ni < 4; ++ni)
#pragma unroll
        for (int r = 0; r < 4; ++r)
          s[mi][ni][r] = __expf(s[mi][ni][r] - mrun[mi][r]);
#pragma unroll
    for (int mi = 0; mi < 2; ++mi)
#pragma unroll
      for (int r = 0; r < 4; ++r) {
        float rs = s[mi][0][r] + s[mi][1][r] + s[mi][2][r] + s[mi][3][r];
        rs = red16_sum(rs);
        lrun[mi][r] = lrun[mi][r] * corr[mi][r] + rs;
      }
#pragma unroll
    for (int mi = 0; mi < 2; ++mi)
#pragma unroll
      for (int ni = 0; ni < 4; ++ni)
#pragma unroll
        for (int r = 0; r < 4; ++r)
          o[mi][ni][r] *= corr[mi][r];

    bf16* Pw = lP[w];
#pragma unroll
    for (int mi = 0; mi < 2; ++mi)
#pragma unroll
      for (int ni = 0; ni < 4; ++ni)
#pragma unroll
        for (int r = 0; r < 4; ++r)
          Pw[(mi * 16 + lg * 4 + r) * 64 + ni * 16 + l15] = (bf16)s[mi][ni][r];

    bf16x8 pa[2][2], vf[4][2];
#pragma unroll
    for (int mi = 0; mi < 2; ++mi)
#pragma unroll
      for (int k2 = 0; k2 < 2; ++k2)
        pa[mi][k2] = *reinterpret_cast<const bf16x8*>(Pw + (mi * 16 + l15) * 64 + k2 * 32 + lg * 8);
#pragma unroll
    for (int ni = 0; ni < 4; ++ni)
#pragma unroll
      for (int k2 = 0; k2 < 2; ++k2)
        vf[ni][k2] = *reinterpret_cast<const bf16x8*>(Vb + (size_t)(ni * 16 + l15) * NKV + kv0 + k2 * 32 + lg * 8);
#pragma unroll
    for (int mi = 0; mi < 2; ++mi)
#pragma unroll
      for (int ni = 0; ni < 4; ++ni)
#pragma unroll
        for (int k2 = 0; k2 < 2; ++k2)
          o[mi][ni] = __builtin_amdgcn_mfma_f32_16x16x32_bf16(pa[mi][k2], vf[ni][k2], o[mi][ni], 0, 0, 0);
  }

  bf16* Ob = out + (size_t)(b * NQ + q0) * DI + h * DH;
#pragma unroll
  for (int mi = 0; mi < 2; ++mi)
#pragma unroll
    for (int r = 0; r < 4; ++r) {
      float inv = 1.0f / lrun[mi][r];
#pragma unroll
      for (int ni = 0; ni < 4; ++ni)
        Ob[(size_t)(mi * 16 + lg * 4 + r) * DI + ni * 16 + l15] = (bf16)(o[mi][ni][r] * inv);
    }
}

// ---------------- launch ----------------
extern "C" void kernel_launch(void* const* d_in, const int* in_sizes, int n_in,
                              void* d_out, int out_size, void* d_ws, size_t ws_size,
                              hipStream_t stream) {
  const float* q     = (const float*)d_in[0];
  const float* ctx   = (const float*)d_in[1];
  const float* Wq    = (const float*)d_in[2];
  const float* Wkv   = (const float*)d_in[3];
  const float* Wproj = (const float*)d_in[4];
  const float* bproj = (const float*)d_in[5];
  const float* qg    = (const float*)d_in[6];
  const float* qb    = (const float*)d_in[7];
  const float* cg    = (const float*)d_in[8];
  const float* cb    = (const float*)d_in[9];

  char* ws = (char*)d_ws;
  bf16* qn    = (bf16*)(ws);                       // 8 MB  (4096x1024)
  bf16* cn    = (bf16*)(ws + ( 8ull << 20));       // 16 MB (8192x1024)
  bf16* Wq_b  = (bf16*)(ws + (24ull << 20));       // 2 MB
  bf16* Wkv_b = (bf16*)(ws + (26ull << 20));       // 4 MB
  bf16* Wp_b  = (bf16*)(ws + (30ull << 20));       // 2 MB
  bf16* qpb   = (bf16*)(ws + (32ull << 20));       // 8 MB  (4096x1024)
  bf16* kbuf  = (bf16*)(ws + (40ull << 20));       // 16 MB (B,NKV,DI)
  bf16* vT    = (bf16*)(ws + (56ull << 20));       // 16 MB (B,DI,NKV)
  bf16* aout  = (bf16*)(ws + (72ull << 20));       // 8 MB  (4096x1024)

  cvt_kernel<<<1024, 256, 0, stream>>>(Wq,    Wq_b,  (1024 * 1024) / 4);
  cvt_kernel<<<2048, 256, 0, stream>>>(Wkv,   Wkv_b, (2048 * 1024) / 4);
  cvt_kernel<<<1024, 256, 0, stream>>>(Wproj, Wp_b,  (1024 * 1024) / 4);
  ln_kernel<<<4096, 256, 0, stream>>>(q,   qg, qb, qn);
  ln_kernel<<<8192, 256, 0, stream>>>(ctx, cg, cb, cn);

  gemm_bt<0><<<256,  256, 0, stream>>>(qn,   Wq_b,  qpb,  nullptr, nullptr, 4096, 1024);
  gemm_bt<1><<<1024, 256, 0, stream>>>(cn,   Wkv_b, kbuf, vT,      nullptr, 8192, 2048);

  attn_kernel<<<dim3(64, 8), 256, 0, stream>>>(qpb, kbuf, vT, aout);

  gemm_bt<2><<<256,  256, 0, stream>>>(aout, Wp_b,  d_out, nullptr, bproj, 4096, 1024);
}